// Round 3
// baseline (228.967 us; speedup 1.0000x reference)
//
#include <hip/hip_runtime.h>
#include <math.h>

// FIRE bias: out[h,i,j] = MLP(nd(i,j)) where
//   nd = log((|i-j|+eps)*c + 1+eps) / log(|c*(max(i,thr)+eps)| + 1+eps)
//   MLP: relu(nd*w1 + b1) dot w2 + b2   (1 -> 32 -> 12)
//
// MLP output per head is piecewise-linear in nd with <=32 breakpoints
// t_w = -b1_w/w1_w. Precompute per-interval (alpha,beta) per head.
// Main kernel: k = #{t_w <= nd} via 32 SGPR compares (no LDS search),
// then 6 x ds_read_b128 for the 12 (alpha,beta) pairs + 12 FMA + 12
// nontemporal float4 stores. Should be HBM-write-bound (201 MB out).

#define SDIM 2048
#define WDIM 32
#define HDIM 12
#define NK 33            // intervals = WDIM + 1
#define EPSF 1e-6f
#define LOGB 1.0f

typedef float v4f __attribute__((ext_vector_type(4)));

// ws layout (floats):
//   [0..63]            sorted thresholds (padded with +INF)
//   [64..64+2*NK*HDIM) interleaved (alpha,beta) per (k,h): ws[64 + k*24 + h*2 + {0,1}]
#define WS_T 0
#define WS_AB 64

__global__ __launch_bounds__(512) void fire_precompute(
    const float* __restrict__ w1, const float* __restrict__ b1,
    const float* __restrict__ w2, const float* __restrict__ b2,
    float* __restrict__ ws)
{
    __shared__ float traw[WDIM], w1s[WDIM], b1s[WDIM];
    __shared__ int rnk[WDIM], neg[WDIM];
    const int tid = threadIdx.x;

    if (tid < WDIM) {
        float a = w1[tid], b = b1[tid];
        w1s[tid] = a; b1s[tid] = b;
        float t; int isneg;
        if (a > 0.f)      { t = -b / a; isneg = 0; }
        else if (a < 0.f) { t = -b / a; isneg = 1; }
        else {
            // w1==0: relu(b1) constant: "always active" if b1>0 else never.
            t = (b > 0.f) ? -INFINITY : INFINITY; isneg = 0;
        }
        traw[tid] = t; neg[tid] = isneg;
    }
    __syncthreads();

    if (tid < WDIM) {
        // rank via O(W^2) counting sort (ties broken by index)
        float t = traw[tid];
        int r = 0;
        for (int v = 0; v < WDIM; ++v) {
            float tv = traw[v];
            if (tv < t || (tv == t && v < tid)) r++;
        }
        rnk[tid] = r;
        ws[WS_T + r] = t;
    } else if (tid < 64) {
        ws[WS_T + tid] = INFINITY;
    }
    __syncthreads();

    // interval k: t_sorted[k-1] <= nd < t_sorted[k]  (k in [0,32])
    // positive-slope unit active iff rank < k; negative-slope iff rank >= k.
    // Boundary assignment is value-neutral (PWL from relu sums is continuous).
    if (tid < NK * HDIM) {
        const int k = tid % NK;
        const int h = tid / NK;
        float a = 0.f, bb = 0.f;
        for (int w = 0; w < WDIM; ++w) {
            const bool active = neg[w] ? (rnk[w] >= k) : (rnk[w] < k);
            if (active) {
                float w2v = w2[h * WDIM + w];
                a  += w2v * w1s[w];
                bb += w2v * b1s[w];
            }
        }
        bb += b2[h];
        ws[WS_AB + k * (2 * HDIM) + h * 2 + 0] = a;
        ws[WS_AB + k * (2 * HDIM) + h * 2 + 1] = bb;
    }
}

__global__ __launch_bounds__(256) void fire_main(
    const float* __restrict__ ws,
    const float* __restrict__ cptr, const float* __restrict__ lmptr,
    const float* __restrict__ ilptr, float* __restrict__ out)
{
    __shared__ float sAB[2 * NK * HDIM];   // 792 floats
    const int tid = threadIdx.x;

    for (int idx = tid; idx < 2 * NK * HDIM; idx += 256) sAB[idx] = ws[WS_AB + idx];

    // thresholds: uniform address -> scalar loads into SGPRs
    float thr_t[WDIM];
    #pragma unroll
    for (int w = 0; w < WDIM; ++w) thr_t[w] = ws[WS_T + w];

    const int i  = blockIdx.x >> 1;             // 2 blocks per row
    const int j0 = ((blockIdx.x & 1) << 10) + tid * 4;

    const float c   = cptr[0];
    const float thr = fabsf(lmptr[0] * ilptr[0]);
    const float pn  = fmaxf((float)i, thr) + EPSF;
    // nd = ln(x)/ln(norm) == log2(x)/log2(norm)
    const float inv_l2n = 1.0f / __log2f(fabsf(c * pn) + LOGB + EPSF);

    __syncthreads();

    float nd[4];
    int   kk[4];
    #pragma unroll
    for (int e = 0; e < 4; ++e) {
        int j = j0 + e;
        int dd = i - j; if (dd < 0) dd = -dd;
        float x = fmaf((float)dd + EPSF, c, LOGB + EPSF);
        float ndv = __log2f(x) * inv_l2n;
        nd[e] = ndv;
        int k = 0;
        #pragma unroll
        for (int w = 0; w < WDIM; ++w) k += (ndv >= thr_t[w]) ? 1 : 0;
        kk[e] = k;
    }

    float o[HDIM][4];
    #pragma unroll
    for (int e = 0; e < 4; ++e) {
        const v4f* abp = (const v4f*)(sAB + kk[e] * (2 * HDIM));  // 96B-aligned
        const float ndv = nd[e];
        #pragma unroll
        for (int m = 0; m < HDIM / 2; ++m) {
            v4f p = abp[m];
            o[2 * m + 0][e] = fmaf(p.x, ndv, p.y);
            o[2 * m + 1][e] = fmaf(p.z, ndv, p.w);
        }
    }

    const size_t base = (size_t)i * SDIM + (size_t)j0;
    #pragma unroll
    for (int h = 0; h < HDIM; ++h) {
        v4f v = { o[h][0], o[h][1], o[h][2], o[h][3] };
        __builtin_nontemporal_store(v, (v4f*)(out + (size_t)h * SDIM * SDIM + base));
    }
}

extern "C" void kernel_launch(void* const* d_in, const int* in_sizes, int n_in,
                              void* d_out, int out_size, void* d_ws, size_t ws_size,
                              hipStream_t stream)
{
    // inputs: 0:x (unused, shape only), 1:w1[32], 2:b1[32], 3:w2[12,32],
    //         4:b2[12], 5:c, 6:L_multiplier, 7:init_L
    const float* w1 = (const float*)d_in[1];
    const float* b1 = (const float*)d_in[2];
    const float* w2 = (const float*)d_in[3];
    const float* b2 = (const float*)d_in[4];
    const float* c  = (const float*)d_in[5];
    const float* lm = (const float*)d_in[6];
    const float* il = (const float*)d_in[7];
    float* ws  = (float*)d_ws;
    float* out = (float*)d_out;

    fire_precompute<<<1, 512, 0, stream>>>(w1, b1, w2, b2, ws);
    fire_main<<<SDIM * 2, 256, 0, stream>>>(ws, c, lm, il, out);
}

// Round 4
// 225.297 us; speedup vs baseline: 1.0163x; 1.0163x over previous
//
#include <hip/hip_runtime.h>
#include <math.h>

// FIRE bias: out[h,i,j] = MLP(nd(i,j)), MLP(1->32->12) is piecewise-linear
// in nd with <=32 breakpoints t_w = -b1_w/w1_w. Precompute per-interval
// (alpha,beta) per head; main kernel: k = #{t_w <= nd} via SGPR compares,
// LDS (alpha,beta) lookup, 12 float4 nt stores.
//
// R4 experiment: blockIdx->row swizzle (odd-multiplier bijection mod 2048)
// so concurrently-resident blocks scatter across the whole 16MB plane ->
// full HBM channel coverage (fill kernel achieves 6.2 TB/s with grid-stride
// dispersion; row-ordered blocks measured ~2.1 TB/s).

#define SDIM 2048
#define WDIM 32
#define HDIM 12
#define NK 33            // intervals = WDIM + 1
#define EPSF 1e-6f
#define LOGB 1.0f

typedef float v4f __attribute__((ext_vector_type(4)));

// ws layout (floats):
//   [0..63]            sorted thresholds (padded with +INF)
//   [64..64+2*NK*HDIM) interleaved (alpha,beta) per (k,h): ws[64 + k*24 + h*2 + {0,1}]
#define WS_T 0
#define WS_AB 64

__global__ __launch_bounds__(512) void fire_precompute(
    const float* __restrict__ w1, const float* __restrict__ b1,
    const float* __restrict__ w2, const float* __restrict__ b2,
    float* __restrict__ ws)
{
    __shared__ float traw[WDIM], w1s[WDIM], b1s[WDIM];
    __shared__ int rnk[WDIM], neg[WDIM];
    const int tid = threadIdx.x;

    if (tid < WDIM) {
        float a = w1[tid], b = b1[tid];
        w1s[tid] = a; b1s[tid] = b;
        float t; int isneg;
        if (a > 0.f)      { t = -b / a; isneg = 0; }
        else if (a < 0.f) { t = -b / a; isneg = 1; }
        else {
            // w1==0: relu(b1) constant: "always active" if b1>0 else never.
            t = (b > 0.f) ? -INFINITY : INFINITY; isneg = 0;
        }
        traw[tid] = t; neg[tid] = isneg;
    }
    __syncthreads();

    if (tid < WDIM) {
        // rank via O(W^2) counting sort (ties broken by index)
        float t = traw[tid];
        int r = 0;
        for (int v = 0; v < WDIM; ++v) {
            float tv = traw[v];
            if (tv < t || (tv == t && v < tid)) r++;
        }
        rnk[tid] = r;
        ws[WS_T + r] = t;
    } else if (tid < 64) {
        ws[WS_T + tid] = INFINITY;
    }
    __syncthreads();

    // interval k: t_sorted[k-1] <= nd < t_sorted[k]  (k in [0,32])
    // positive-slope unit active iff rank < k; negative-slope iff rank >= k.
    // Boundary assignment is value-neutral (PWL from relu sums is continuous).
    if (tid < NK * HDIM) {
        const int k = tid % NK;
        const int h = tid / NK;
        float a = 0.f, bb = 0.f;
        for (int w = 0; w < WDIM; ++w) {
            const bool active = neg[w] ? (rnk[w] >= k) : (rnk[w] < k);
            if (active) {
                float w2v = w2[h * WDIM + w];
                a  += w2v * w1s[w];
                bb += w2v * b1s[w];
            }
        }
        bb += b2[h];
        ws[WS_AB + k * (2 * HDIM) + h * 2 + 0] = a;
        ws[WS_AB + k * (2 * HDIM) + h * 2 + 1] = bb;
    }
}

__global__ __launch_bounds__(256) void fire_main(
    const float* __restrict__ ws,
    const float* __restrict__ cptr, const float* __restrict__ lmptr,
    const float* __restrict__ ilptr, float* __restrict__ out)
{
    __shared__ float sAB[2 * NK * HDIM];   // 792 floats
    const int tid = threadIdx.x;

    for (int idx = tid; idx < 2 * NK * HDIM; idx += 256) sAB[idx] = ws[WS_AB + idx];

    // thresholds: uniform address -> scalar loads into SGPRs
    float thr_t[WDIM];
    #pragma unroll
    for (int w = 0; w < WDIM; ++w) thr_t[w] = ws[WS_T + w];

    // Row swizzle: consecutive blocks hit rows ~331 apart (odd multiplier ->
    // bijection mod 2048) so the resident set spans the whole plane and all
    // HBM channels stay busy.
    const int i  = ((blockIdx.x >> 1) * 331) & (SDIM - 1);
    const int j0 = ((blockIdx.x & 1) << 10) + tid * 4;

    const float c   = cptr[0];
    const float thr = fabsf(lmptr[0] * ilptr[0]);
    const float pn  = fmaxf((float)i, thr) + EPSF;
    // nd = ln(x)/ln(norm) == log2(x)/log2(norm)
    const float inv_l2n = 1.0f / __log2f(fabsf(c * pn) + LOGB + EPSF);

    __syncthreads();

    float nd[4];
    int   kk[4];
    #pragma unroll
    for (int e = 0; e < 4; ++e) {
        int j = j0 + e;
        int dd = i - j; if (dd < 0) dd = -dd;
        float x = fmaf((float)dd + EPSF, c, LOGB + EPSF);
        float ndv = __log2f(x) * inv_l2n;
        nd[e] = ndv;
        int k = 0;
        #pragma unroll
        for (int w = 0; w < WDIM; ++w) k += (ndv >= thr_t[w]) ? 1 : 0;
        kk[e] = k;
    }

    float o[HDIM][4];
    #pragma unroll
    for (int e = 0; e < 4; ++e) {
        const v4f* abp = (const v4f*)(sAB + kk[e] * (2 * HDIM));  // 96B rows
        const float ndv = nd[e];
        #pragma unroll
        for (int m = 0; m < HDIM / 2; ++m) {
            v4f p = abp[m];
            o[2 * m + 0][e] = fmaf(p.x, ndv, p.y);
            o[2 * m + 1][e] = fmaf(p.z, ndv, p.w);
        }
    }

    const size_t base = (size_t)i * SDIM + (size_t)j0;
    #pragma unroll
    for (int h = 0; h < HDIM; ++h) {
        v4f v = { o[h][0], o[h][1], o[h][2], o[h][3] };
        __builtin_nontemporal_store(v, (v4f*)(out + (size_t)h * SDIM * SDIM + base));
    }
}

extern "C" void kernel_launch(void* const* d_in, const int* in_sizes, int n_in,
                              void* d_out, int out_size, void* d_ws, size_t ws_size,
                              hipStream_t stream)
{
    // inputs: 0:x (unused, shape only), 1:w1[32], 2:b1[32], 3:w2[12,32],
    //         4:b2[12], 5:c, 6:L_multiplier, 7:init_L
    const float* w1 = (const float*)d_in[1];
    const float* b1 = (const float*)d_in[2];
    const float* w2 = (const float*)d_in[3];
    const float* b2 = (const float*)d_in[4];
    const float* c  = (const float*)d_in[5];
    const float* lm = (const float*)d_in[6];
    const float* il = (const float*)d_in[7];
    float* ws  = (float*)d_ws;
    float* out = (float*)d_out;

    fire_precompute<<<1, 512, 0, stream>>>(w1, b1, w2, b2, ws);
    fire_main<<<SDIM * 2, 256, 0, stream>>>(ws, c, lm, il, out);
}